// Round 1
// baseline (277.631 us; speedup 1.0000x reference)
//
#include <hip/hip_runtime.h>
#include <math.h>

#define BB 32
#define CC 384
#define HH 56
#define WW 56
#define KK 7
#define HWSZ (HH*WW)          // 3136
#define EPSF 1e-6f
#define LDS_S 64              // LDS row stride (floats) for conv tile

// ---------------- kernel 1: per-(b,c) mean + max over H*W ----------------
__global__ __launch_bounds__(256) void pool_kernel(const float* __restrict__ x,
                                                   float* __restrict__ xavg,
                                                   float* __restrict__ xmax) {
    int plane = blockIdx.x;                       // b*C + c
    const float4* xp = (const float4*)(x + (size_t)plane * HWSZ);
    int t = threadIdx.x;
    float s = 0.f, m = -INFINITY;
    for (int i = t; i < HWSZ/4; i += 256) {       // 784 float4
        float4 v = xp[i];
        s += v.x + v.y + v.z + v.w;
        m = fmaxf(m, fmaxf(fmaxf(v.x, v.y), fmaxf(v.z, v.w)));
    }
    for (int off = 32; off; off >>= 1) {
        s += __shfl_down(s, off, 64);
        m = fmaxf(m, __shfl_down(m, off, 64));
    }
    __shared__ float ss[4], sm[4];
    int wid = t >> 6;
    if ((t & 63) == 0) { ss[wid] = s; sm[wid] = m; }
    __syncthreads();
    if (t == 0) {
        s = ss[0] + ss[1] + ss[2] + ss[3];
        m = fmaxf(fmaxf(sm[0], sm[1]), fmaxf(sm[2], sm[3]));
        xavg[plane] = s * (1.0f / HWSZ);
        xmax[plane] = m;
    }
}

// ---------------- kernel 2: GEMVs + GELU + FGRN -> per-sample 7x7 kernels ----------------
// one block per batch element b, 384 threads (thread = output channel c)
__global__ __launch_bounds__(384) void weights_kernel(
        const float* __restrict__ xavg, const float* __restrict__ xmax,
        const float* __restrict__ w_avg, const float* __restrict__ b_avg,
        const float* __restrict__ w_max, const float* __restrict__ b_max,
        const float* __restrict__ w_mix, const float* __restrict__ gamma,
        const float* __restrict__ beta, float* __restrict__ kern) {
    int b = blockIdx.x, c = threadIdx.x;
    __shared__ float xa[CC], xm[CC], red[512];
    xa[c] = xavg[b*CC + c];
    xm[c] = xmax[b*CC + c];
    if (c < 512 - CC) red[CC + c] = 0.f;
    __syncthreads();

    // out[b,c] = sum_k xa[k]*w_avg[c,k] + xm[k]*w_max[c,k] + biases
    const float4* wa = (const float4*)(w_avg + (size_t)c * CC);
    const float4* wm = (const float4*)(w_max + (size_t)c * CC);
    float acc = b_avg[c] + b_max[c];
    #pragma unroll 4
    for (int q = 0; q < CC/4; ++q) {
        float4 a4 = wa[q], m4 = wm[q];
        const float* xap = &xa[q*4];
        const float* xmp = &xm[q*4];
        acc += a4.x*xap[0] + a4.y*xap[1] + a4.z*xap[2] + a4.w*xap[3];
        acc += m4.x*xmp[0] + m4.y*xmp[1] + m4.z*xmp[2] + m4.w*xmp[3];
    }
    // exact GELU: 0.5*x*(1+erf(x/sqrt(2)))
    float xw = 0.5f * acc * (1.0f + erff(acc * 0.70710678118654752f));

    // Gx = |xw| * ||w_mix[c,:]||
    float wrow[49];
    float sq = 0.f;
    const float* wmx = w_mix + c*49;
    #pragma unroll
    for (int j = 0; j < 49; ++j) { wrow[j] = wmx[j]; sq += wrow[j]*wrow[j]; }
    float Gx = fabsf(xw) * sqrtf(sq);

    red[c] = Gx;
    __syncthreads();
    for (int off = 256; off > 0; off >>= 1) {
        if (c < off) red[c] += red[c + off];
        __syncthreads();
    }
    float meanG = red[0] * (1.0f / CC);
    float Nx = Gx / (meanG + EPSF);

    float g = gamma[c], bt = beta[c];
    float coef = g * xw * Nx;
    float* kp = kern + ((size_t)(b*CC + c)) * 49;
    #pragma unroll
    for (int j = 0; j < 49; ++j) kp[j] = coef * wrow[j] + bt;
}

// ---------------- kernel 3: dynamic depthwise 7x7 conv ----------------
// one block per (b,c) plane; LDS-staged 62x62 zero-padded tile
__global__ __launch_bounds__(256) void conv_kernel(const float* __restrict__ x,
                                                   const float* __restrict__ kern,
                                                   float* __restrict__ out) {
    int plane = blockIdx.x;
    const float* xp = x + (size_t)plane * HWSZ;
    float* op = out + (size_t)plane * HWSZ;

    __shared__ float tile[(HH + 6) * LDS_S];   // 62 rows x 64 stride
    __shared__ float kf[49];
    int t = threadIdx.x;

    if (t < 49) kf[t] = kern[(size_t)plane * 49 + t];
    for (int i = t; i < (HH + 6) * LDS_S; i += 256) tile[i] = 0.f;
    __syncthreads();

    const float4* xp4 = (const float4*)xp;
    for (int i = t; i < HWSZ/4; i += 256) {      // 784 float4, rows of 14
        float4 v = xp4[i];
        int row = i / (WW/4);
        int c4  = (i % (WW/4)) * 4;
        float* dst = &tile[(row + 3) * LDS_S + 3 + c4];
        dst[0] = v.x; dst[1] = v.y; dst[2] = v.z; dst[3] = v.w;
    }
    __syncthreads();

    for (int s4 = t; s4 < HWSZ/4; s4 += 256) {
        int row = s4 / (WW/4);
        int c0  = (s4 % (WW/4)) * 4;             // output cols c0..c0+3
        float a0 = 0.f, a1 = 0.f, a2 = 0.f, a3 = 0.f;
        #pragma unroll
        for (int ky = 0; ky < 7; ++ky) {
            const float* rp = &tile[(row + ky) * LDS_S + c0];  // 16B aligned
            float rv[10];
            #pragma unroll
            for (int q = 0; q < 10; ++q) rv[q] = rp[q];
            #pragma unroll
            for (int kx = 0; kx < 7; ++kx) {
                float kv = kf[ky*7 + kx];
                a0 = fmaf(kv, rv[kx],     a0);
                a1 = fmaf(kv, rv[kx + 1], a1);
                a2 = fmaf(kv, rv[kx + 2], a2);
                a3 = fmaf(kv, rv[kx + 3], a3);
            }
        }
        float4 o; o.x = a0; o.y = a1; o.z = a2; o.w = a3;
        ((float4*)op)[s4] = o;
    }
}

extern "C" void kernel_launch(void* const* d_in, const int* in_sizes, int n_in,
                              void* d_out, int out_size, void* d_ws, size_t ws_size,
                              hipStream_t stream) {
    const float* x     = (const float*)d_in[0];
    const float* w_avg = (const float*)d_in[1];
    const float* b_avg = (const float*)d_in[2];
    const float* w_max = (const float*)d_in[3];
    const float* b_max = (const float*)d_in[4];
    const float* w_mix = (const float*)d_in[5];
    const float* gamma = (const float*)d_in[6];
    const float* beta  = (const float*)d_in[7];
    float* out = (float*)d_out;

    float* ws   = (float*)d_ws;
    float* xavg = ws;                       // B*C
    float* xmax = ws + BB*CC;               // B*C
    float* kern = ws + 2*BB*CC;             // B*C*49

    pool_kernel<<<BB*CC, 256, 0, stream>>>(x, xavg, xmax);
    weights_kernel<<<BB, CC, 0, stream>>>(xavg, xmax, w_avg, b_avg, w_max, b_max,
                                          w_mix, gamma, beta, kern);
    conv_kernel<<<BB*CC, 256, 0, stream>>>(x, kern, out);
}

// Round 2
// 158.643 us; speedup vs baseline: 1.7500x; 1.7500x over previous
//
#include <hip/hip_runtime.h>
#include <math.h>

#define BB 32
#define CC 384
#define HH 56
#define WW 56
#define KK 7
#define HWSZ (HH*WW)          // 3136
#define EPSF 1e-6f
#define TS 68                 // LDS row stride (floats): 16B-aligned, 16-bank skew per row
#define TROWS 62              // 56 + 3 top + 3 bottom
// tile col = input col + 4 (left pad 4 keeps both writes and reads 16B aligned)

// ---------------- kernel 1: per-(b,c) mean + max over H*W ----------------
__global__ __launch_bounds__(256) void pool_kernel(const float* __restrict__ x,
                                                   float* __restrict__ xavg,
                                                   float* __restrict__ xmax) {
    int plane = blockIdx.x;                       // b*C + c
    const float4* xp = (const float4*)(x + (size_t)plane * HWSZ);
    int t = threadIdx.x;
    float s = 0.f, m = -INFINITY;
    for (int i = t; i < HWSZ/4; i += 256) {       // 784 float4
        float4 v = xp[i];
        s += v.x + v.y + v.z + v.w;
        m = fmaxf(m, fmaxf(fmaxf(v.x, v.y), fmaxf(v.z, v.w)));
    }
    for (int off = 32; off; off >>= 1) {
        s += __shfl_down(s, off, 64);
        m = fmaxf(m, __shfl_down(m, off, 64));
    }
    __shared__ float ss[4], sm[4];
    int wid = t >> 6;
    if ((t & 63) == 0) { ss[wid] = s; sm[wid] = m; }
    __syncthreads();
    if (t == 0) {
        s = ss[0] + ss[1] + ss[2] + ss[3];
        m = fmaxf(fmaxf(sm[0], sm[1]), fmaxf(sm[2], sm[3]));
        xavg[plane] = s * (1.0f / HWSZ);
        xmax[plane] = m;
    }
}

// ---------------- kernel 2: GEMVs + GELU + FGRN -> per-sample 7x7 kernels ----------------
__global__ __launch_bounds__(384) void weights_kernel(
        const float* __restrict__ xavg, const float* __restrict__ xmax,
        const float* __restrict__ w_avg, const float* __restrict__ b_avg,
        const float* __restrict__ w_max, const float* __restrict__ b_max,
        const float* __restrict__ w_mix, const float* __restrict__ gamma,
        const float* __restrict__ beta, float* __restrict__ kern) {
    int b = blockIdx.x, c = threadIdx.x;
    __shared__ float xa[CC], xm[CC], red[512];
    xa[c] = xavg[b*CC + c];
    xm[c] = xmax[b*CC + c];
    if (c < 512 - CC) red[CC + c] = 0.f;
    __syncthreads();

    const float4* wa = (const float4*)(w_avg + (size_t)c * CC);
    const float4* wm = (const float4*)(w_max + (size_t)c * CC);
    float acc = b_avg[c] + b_max[c];
    #pragma unroll 4
    for (int q = 0; q < CC/4; ++q) {
        float4 a4 = wa[q], m4 = wm[q];
        const float* xap = &xa[q*4];
        const float* xmp = &xm[q*4];
        acc += a4.x*xap[0] + a4.y*xap[1] + a4.z*xap[2] + a4.w*xap[3];
        acc += m4.x*xmp[0] + m4.y*xmp[1] + m4.z*xmp[2] + m4.w*xmp[3];
    }
    float xw = 0.5f * acc * (1.0f + erff(acc * 0.70710678118654752f));

    float wrow[49];
    float sq = 0.f;
    const float* wmx = w_mix + c*49;
    #pragma unroll
    for (int j = 0; j < 49; ++j) { wrow[j] = wmx[j]; sq += wrow[j]*wrow[j]; }
    float Gx = fabsf(xw) * sqrtf(sq);

    red[c] = Gx;
    __syncthreads();
    for (int off = 256; off > 0; off >>= 1) {
        if (c < off) red[c] += red[c + off];
        __syncthreads();
    }
    float meanG = red[0] * (1.0f / CC);
    float Nx = Gx / (meanG + EPSF);

    float g = gamma[c], bt = beta[c];
    float coef = g * xw * Nx;
    float* kp = kern + ((size_t)(b*CC + c)) * 49;
    #pragma unroll
    for (int j = 0; j < 49; ++j) kp[j] = coef * wrow[j] + bt;
}

// ---------------- kernel 3: dynamic depthwise 7x7 conv ----------------
// one block per (b,c) plane; each lane computes a 4x4 output patch
__global__ __launch_bounds__(256) void conv_kernel(const float* __restrict__ x,
                                                   const float* __restrict__ kern,
                                                   float* __restrict__ out) {
    int plane = blockIdx.x;
    const float* xp = x + (size_t)plane * HWSZ;
    float* op = out + (size_t)plane * HWSZ;
    int t = threadIdx.x;

    __shared__ float tile[TROWS * TS];   // 62 x 68 floats = 16864 B

    // kernel taps -> wave-uniform SGPRs (zero LDS traffic in the hot loop)
    float kfv[49];
    {
        const float* kp = kern + (size_t)plane * 49;
        #pragma unroll
        for (int j = 0; j < 49; ++j) {
            union { float f; int i; } u;
            u.f = kp[j];
            u.i = __builtin_amdgcn_readfirstlane(u.i);
            kfv[j] = u.f;
        }
    }

    // zero-init tile (borders need zeros; zero it all, it's cheap)
    for (int i = t; i < (TROWS * TS) / 4; i += 256)
        ((float4*)tile)[i] = make_float4(0.f, 0.f, 0.f, 0.f);
    __syncthreads();

    // stage plane: input (row, col4) -> tile[(row+3)*TS + 4 + col4], 16B aligned
    const float4* xp4 = (const float4*)xp;
    for (int i = t; i < HWSZ/4; i += 256) {      // 784 float4
        int row = i / (WW/4);
        int c4  = (i - row*(WW/4)) * 4;
        *((float4*)&tile[(row + 3) * TS + 4 + c4]) = xp4[i];
    }
    __syncthreads();

    // lane -> 4x4 patch: rows [gc*4, gc*4+4), cols [sc*4, sc*4+4)
    int s = t & 15, g = t >> 4;
    int sc = (s < 14) ? s : 0;                   // clamp: inactive lanes recompute patch 0
    int gc = (g < 14) ? g : 0;
    bool active = (s < 14) && (g < 14);
    int r0 = gc * 4;
    int c0 = sc * 4;

    float acc[4][4];
    #pragma unroll
    for (int i = 0; i < 4; ++i)
        #pragma unroll
        for (int j = 0; j < 4; ++j) acc[i][j] = 0.f;

    // out(r0+oy, c0+j) = sum_{ky,kx} k[ky][kx] * tile[r0+oy+ky][c0+j+kx+1]
    // iterate tile rows ry = 0..9; row contributes to oy in [max(0,ry-6), min(3,ry)], ky = ry-oy
    #pragma unroll
    for (int ry = 0; ry < 10; ++ry) {
        const float* rp = &tile[(r0 + ry) * TS + c0];   // 16B aligned
        float rv[12];
        #pragma unroll
        for (int q = 0; q < 3; ++q)
            *((float4*)&rv[q*4]) = *((const float4*)&rp[q*4]);

        int oy_lo = (ry - 6 > 0) ? (ry - 6) : 0;
        int oy_hi = (ry < 3) ? ry : 3;
        #pragma unroll
        for (int oy = 0; oy < 4; ++oy) {
            if (oy < oy_lo || oy > oy_hi) continue;
            int ky = ry - oy;
            #pragma unroll
            for (int kx = 0; kx < 7; ++kx) {
                float kv = kfv[ky*7 + kx];
                #pragma unroll
                for (int j = 0; j < 4; ++j)
                    acc[oy][j] = fmaf(kv, rv[j + 1 + kx], acc[oy][j]);
            }
        }
    }

    if (active) {
        #pragma unroll
        for (int oy = 0; oy < 4; ++oy) {
            float4 o; o.x = acc[oy][0]; o.y = acc[oy][1]; o.z = acc[oy][2]; o.w = acc[oy][3];
            ((float4*)op)[(r0 + oy) * (WW/4) + sc] = o;
        }
    }
}

extern "C" void kernel_launch(void* const* d_in, const int* in_sizes, int n_in,
                              void* d_out, int out_size, void* d_ws, size_t ws_size,
                              hipStream_t stream) {
    const float* x     = (const float*)d_in[0];
    const float* w_avg = (const float*)d_in[1];
    const float* b_avg = (const float*)d_in[2];
    const float* w_max = (const float*)d_in[3];
    const float* b_max = (const float*)d_in[4];
    const float* w_mix = (const float*)d_in[5];
    const float* gamma = (const float*)d_in[6];
    const float* beta  = (const float*)d_in[7];
    float* out = (float*)d_out;

    float* ws   = (float*)d_ws;
    float* xavg = ws;                       // B*C
    float* xmax = ws + BB*CC;               // B*C
    float* kern = ws + 2*BB*CC;             // B*C*49

    pool_kernel<<<BB*CC, 256, 0, stream>>>(x, xavg, xmax);
    weights_kernel<<<BB, CC, 0, stream>>>(xavg, xmax, w_avg, b_avg, w_max, b_max,
                                          w_mix, gamma, beta, kern);
    conv_kernel<<<BB*CC, 256, 0, stream>>>(x, kern, out);
}